// Round 7
// baseline (158.494 us; speedup 1.0000x reference)
//
#include <hip/hip_runtime.h>
#include <cmath>

// SSIM stability loss: 1 - mean(SSIM(x,y)), 11x11 Gaussian (sigma=1.5), zero SAME
// padding, fp32, 32 x 1 x 512 x 512.
//
// R6 -> R7: cross-round accounting shows dur == VALU_cycles / VALUBusy every
// round, and only R1's phase structure (stage whole band once -> one barrier ->
// long uninterrupted compute) reached 65% VALUBusy; all streamed-chunk variants
// (R4/R5/R6, with or without barriers) are pinned at 30-34% by the per-chunk
// load/wait/write/read cadence. So: R1 geometry (128x32 tile, 2 strips x 16
// rows, whole 42-row band in LDS, ONE barrier) combined with R4 efficiency
// (packed v2f (x,y) math -> ds_read_b64 + v_pk_fma_f32, float4 staging,
// circular 11-deep register history, single dispatch + fp64 atomic finish).
//
// LDS: 42 x 144 x 8 B = 48384 B -> 3 blocks/CU = 12 waves/CU (R1-proven busy).
// Per strip: 26 H-rows (16 out + 10 halo; rows 16..25 recomputed by both
// strips = 1.24x H overhead, cheaper than round-tripping H results via LDS).

#define IMG    512
#define TILE_W 128
#define TILE_H 32
#define NHR    26          // H-rows per strip
#define NROWS  42          // staged rows = TILE_H + 10
#define LCOLS  144         // staged cols (mult of 4; covers c0-8 .. c0+135)
#define UPR    36          // float4 units per staged row
#define NUNITS (NROWS * UPR)   // 1512
#define NBLOCKS 2048
#define NPIX   8388608.0

typedef float v2f __attribute__((ext_vector_type(2)));

struct GaussW { float w[11]; };

__global__ __launch_bounds__(256)
void ssim_band_kernel(const float* __restrict__ x, const float* __restrict__ y,
                      double* __restrict__ acc_ws, unsigned long long* __restrict__ ctr,
                      float* __restrict__ out, GaussW gw) {
    __shared__ v2f tile[NROWS][LCOLS];    // (x,y) interleaved; 48384 B
    __shared__ float wavesum[4];

    const int tid = threadIdx.x;
    const int c0 = blockIdx.x * TILE_W;
    const int r0 = blockIdx.y * TILE_H;
    const size_t img_off = (size_t)blockIdx.z * (IMG * IMG);
    const float* __restrict__ xb = x + img_off;
    const float* __restrict__ yb = y + img_off;

    // ---- Phase A: stage whole band (42 rows) once; float4 global loads ----
    #pragma unroll
    for (int it = 0; it < 6; ++it) {
        int idx = tid + it * 256;          // 0..1535; guard < 1512
        int row = idx / UPR;
        int u   = idx - row * UPR;
        int gr = r0 - 5 + row;
        int gc = c0 - 8 + u * 4;           // 16B-aligned global col
        float4 vx = make_float4(0.f, 0.f, 0.f, 0.f);
        float4 vy = vx;
        if (idx < NUNITS && (unsigned)gr < IMG && (unsigned)gc < IMG) {
            const float* px = xb + (size_t)gr * IMG + gc;
            const float* py = yb + (size_t)gr * IMG + gc;
            vx = *(const float4*)px;
            vy = *(const float4*)py;
        }
        if (idx < NUNITS) {
            v2f* dst = &tile[row][u * 4];
            dst[0] = (v2f){vx.x, vy.x};
            dst[1] = (v2f){vx.y, vy.y};
            dst[2] = (v2f){vx.z, vy.z};
            dst[3] = (v2f){vx.w, vy.w};
        }
    }
    __syncthreads();                       // the only barrier before the reduction

    // ---- Phase B: per-strip compute, fully unrolled, zero further syncs ----
    const int ci    = tid & (TILE_W - 1);  // taps at LDS cols ci+3 .. ci+13
    const int strip = tid >> 7;            // 0 or 1
    const int rbase = strip * 16;          // strip's first H-row

    v2f wp[11];
    #pragma unroll
    for (int k = 0; k < 11; ++k) { wp[k][0] = gw.w[k]; wp[k][1] = gw.w[k]; }

    v2f hist01[11];    // (hx, hy)
    v2f hist23[11];    // (hxx, hyy)
    float hist4[11];   // hxy
    float lsum = 0.f;
    const float C1 = 1e-4f, C2 = 9e-4f;

    #pragma unroll
    for (int r = 0; r < NHR; ++r) {        // H-row rbase+r; hist slot r%11
        // --- horizontal 11-tap conv, packed channels ---
        v2f h01 = (v2f){0.f, 0.f};
        v2f h23 = (v2f){0.f, 0.f};
        float h4 = 0.f;
        #pragma unroll
        for (int k = 0; k < 11; ++k) {
            v2f t = tile[rbase + r][ci + 3 + k];
            v2f tt = wp[k] * t;                               // pk_mul
            h01 = __builtin_elementwise_fma(wp[k], t, h01);   // pk_fma
            h23 = __builtin_elementwise_fma(tt, t, h23);      // pk_fma
            h4 = fmaf(tt[0], t[1], h4);                       // wk*x*y
        }
        const int slot = r % 11;
        hist01[slot] = h01; hist23[slot] = h23; hist4[slot] = h4;

        // --- output row (r-10) completes now ---
        if (r >= 10) {                     // compile-time (fully unrolled)
            v2f a01 = (v2f){0.f, 0.f};
            v2f a23 = (v2f){0.f, 0.f};
            float a4 = 0.f;
            #pragma unroll
            for (int j = 0; j < 11; ++j) {
                const int sl = (r + 1 + j) % 11;   // static per (r,j)
                a01 = __builtin_elementwise_fma(wp[j], hist01[sl], a01);
                a23 = __builtin_elementwise_fma(wp[j], hist23[sl], a23);
                a4 = fmaf(wp[j][0], hist4[sl], a4);
            }
            float mx = a01[0], my = a01[1];
            float mxx = mx * mx, myy = my * my, mxy = mx * my;
            float sxx = a23[0] - mxx, syy = a23[1] - myy, sxy = a4 - mxy;
            float num = (2.f * mxy + C1) * (2.f * sxy + C2);
            float den = (mxx + myy + C1) * (sxx + syy + C2);
            lsum += num * __builtin_amdgcn_rcpf(den);
        }
    }

    // ---- reduction: wave shuffle -> LDS -> block partial -> fp64 atomic ----
    #pragma unroll
    for (int off = 32; off > 0; off >>= 1)
        lsum += __shfl_down(lsum, off, 64);
    if ((tid & 63) == 0) wavesum[tid >> 6] = lsum;
    __syncthreads();
    if (tid == 0) {
        float bs = wavesum[0] + wavesum[1] + wavesum[2] + wavesum[3];
        atomicAdd(acc_ws, (double)bs);
        __threadfence();
        unsigned long long old = atomicAdd(ctr, 1ull);
        if (old == (unsigned long long)(NBLOCKS - 1)) {
            __threadfence();
            double total = atomicAdd(acc_ws, 0.0);   // atomic RMW sees all prior adds
            out[0] = (float)(1.0 - total / NPIX);
        }
    }
}

extern "C" void kernel_launch(void* const* d_in, const int* in_sizes, int n_in,
                              void* d_out, int out_size, void* d_ws, size_t ws_size,
                              hipStream_t stream) {
    const float* x = (const float*)d_in[0];   // heatmap_clean
    const float* y = (const float*)d_in[1];   // heatmap_adv
    float* out = (float*)d_out;
    double* acc = (double*)d_ws;
    unsigned long long* ctr = (unsigned long long*)((char*)d_ws + 8);

    // zero the 16B of accumulator+counter state (capture-safe async memset)
    hipMemsetAsync(d_ws, 0, 16, stream);

    GaussW gw;
    double g[11], s = 0.0;
    for (int i = 0; i < 11; ++i) { double d = i - 5; g[i] = exp(-(d * d) / 4.5); s += g[i]; }
    for (int i = 0; i < 11; ++i) gw.w[i] = (float)(g[i] / s);

    dim3 grid(IMG / TILE_W, IMG / TILE_H, 32);   // (4, 16, 32) = 2048 blocks
    ssim_band_kernel<<<grid, 256, 0, stream>>>(x, y, acc, ctr, out, gw);
}

// Round 8
// 133.318 us; speedup vs baseline: 1.1888x; 1.1888x over previous
//
#include <hip/hip_runtime.h>
#include <cmath>

// SSIM stability loss: 1 - mean(SSIM(x,y)), 11x11 Gaussian (sigma=1.5), zero SAME
// padding, fp32, 32 x 1 x 512 x 512.
//
// R4 structure (best measured: 74 us kernel): 256 threads = 256 cols x 32-row
// band, 42 H-rows streamed through an 11-row LDS chunk, packed v2f math,
// 11-deep circular register history, single dispatch + fp64 atomic finish.
//
// R7 -> R8: every structural variant (barriers/none, 1-8 blocks/CU, 24-48 KB
// LDS) pins at 72-97 us with all pipes <40%; busy-cycles track static instr
// counts, so the remaining dense instruction stream is LDS reads (11
// ds_read_b64 per H-row per thread). This round: store col pairs as v4f
// (x0,y0,x1,y1) 16-B units and read each 11-tap window as 6 ALIGNED
// ds_read_b128 covering 12 cols; per-lane alignment parity is folded into a
// 12-tap weight vector (one end weight = 0, selected per lane at init) --
// branchless, every tap operand is an adjacent v2f half of a loaded v4f.
// LDS read instrs -45%, H VALU +9% (12 taps vs 11).

#define IMG   512
#define BROWS 32
#define NCHUNK 4          // ceil(42/11)
#define CHR   11          // rows per LDS chunk (== history depth)
#define LCOLS 272         // staged cols per row (covers c0-8 .. c0+263)
#define LUNITS 68         // float4 units per staged row
#define NUNITS (CHR * LUNITS)   // 748
#define NBLOCKS 1024
#define NPIX  8388608.0

typedef float v2f __attribute__((ext_vector_type(2)));
typedef float v4f __attribute__((ext_vector_type(4)));

struct GaussW { float w[11]; };

__global__ __launch_bounds__(256)
void ssim_stream_kernel(const float* __restrict__ x, const float* __restrict__ y,
                        double* __restrict__ acc_ws, unsigned long long* __restrict__ ctr,
                        float* __restrict__ out, GaussW gw) {
    // tile4[s][u] = LDS cols (2u, 2u+1) packed as (x0, y0, x1, y1); 16-B units
    __shared__ v4f tile4[CHR][LCOLS / 2];   // 11 * 136 * 16 = 23936 B
    __shared__ float wavesum[4];

    const int tid = threadIdx.x;
    const int c0 = blockIdx.x * 256;
    const int r0 = blockIdx.y * BROWS;
    const size_t img_off = (size_t)blockIdx.z * (IMG * IMG);
    const float* __restrict__ xb = x + img_off;
    const float* __restrict__ yb = y + img_off;

    const int ci = tid;                 // output column; taps at LDS cols ci+3..ci+13
    const int ub = (ci + 3) >> 1;       // v4f unit of aligned window base
    const int p  = (ci + 3) & 1;        // parity: tap k sits at window pos p+k

    // 12-tap per-lane weight vector: window pos m covers LDS col 2*ub + m;
    // logical tap k = m - p, so wv2[m] = w[m-p] (0 outside [0,10]).
    v2f wv2[12];
    #pragma unroll
    for (int m = 0; m < 12; ++m) {
        float lo = (m <= 10) ? gw.w[m] : 0.f;       // p == 0
        float hi = (m >= 1) ? gw.w[m - 1] : 0.f;    // p == 1
        float wm = p ? hi : lo;
        wv2[m][0] = wm; wv2[m][1] = wm;
    }
    v2f wp[11];                          // vertical weights (parity-free)
    #pragma unroll
    for (int k = 0; k < 11; ++k) { wp[k][0] = gw.w[k]; wp[k][1] = gw.w[k]; }

    float4 sxr[3], syr[3];   // staged regs for next chunk (3 iters x 256 thr >= 748)

    auto load_chunk = [&](int c) {
        #pragma unroll
        for (int it = 0; it < 3; ++it) {
            int idx = tid + it * 256;
            int row = idx / LUNITS;
            int u   = idx - row * LUNITS;
            int gr = r0 - 5 + c * CHR + row;       // global image row
            int gc = c0 - 8 + u * 4;               // global col of float4 (16B aligned)
            float4 vx = make_float4(0.f, 0.f, 0.f, 0.f);
            float4 vy = vx;
            if (idx < NUNITS && (unsigned)gr < IMG && (unsigned)gc < IMG) {
                const float* px = xb + (size_t)gr * IMG + gc;
                const float* py = yb + (size_t)gr * IMG + gc;
                vx = *(const float4*)px;
                vy = *(const float4*)py;
            }
            sxr[it] = vx; syr[it] = vy;
        }
    };
    auto store_chunk = [&]() {
        #pragma unroll
        for (int it = 0; it < 3; ++it) {
            int idx = tid + it * 256;
            if (idx < NUNITS) {
                int row = idx / LUNITS;
                int u   = idx - row * LUNITS;
                tile4[row][u * 2]     = (v4f){sxr[it].x, syr[it].x, sxr[it].y, syr[it].y};
                tile4[row][u * 2 + 1] = (v4f){sxr[it].z, syr[it].z, sxr[it].w, syr[it].w};
            }
        }
    };

    v2f hist01[11];    // (hx, hy)
    v2f hist23[11];    // (hxx, hyy)
    float hist4[11];   // hxy
    float lsum = 0.f;
    const float C1 = 1e-4f, C2 = 9e-4f;

    load_chunk(0);
    store_chunk();
    __syncthreads();

    #pragma unroll 1
    for (int c = 0; c < NCHUNK; ++c) {      // 4 chunks x 11 rows = 44 >= 42
        if (c < NCHUNK - 1) load_chunk(c + 1);  // global loads overlap chunk-c compute

        #pragma unroll
        for (int s = 0; s < CHR; ++s) {     // H-row m = 11c + s; hist slot = s
            if (!(c == NCHUNK - 1 && s >= 9)) {   // m < 42 (wave-uniform guard)
                // --- horizontal conv: 6 aligned b128 window loads, 12 taps ---
                v4f w6[6];
                #pragma unroll
                for (int i = 0; i < 6; ++i) w6[i] = tile4[s][ub + i];
                v2f h01 = (v2f){0.f, 0.f};
                v2f h23 = (v2f){0.f, 0.f};
                float h4 = 0.f;
                #pragma unroll
                for (int m = 0; m < 12; ++m) {
                    v2f t = (m & 1) ? w6[m >> 1].zw : w6[m >> 1].xy;
                    v2f tw = wv2[m] * t;                          // pk_mul
                    h01 += tw;                                    // pk_add
                    h23 = __builtin_elementwise_fma(tw, t, h23);  // pk_fma
                    h4 = fmaf(tw[0], t[1], h4);                   // w*x*y
                }
                hist01[s] = h01; hist23[s] = h23; hist4[s] = h4;

                // --- output row (11c + s - 10) completes now ---
                if (c > 0 || s == 10) {
                    v2f a01 = (v2f){0.f, 0.f};
                    v2f a23 = (v2f){0.f, 0.f};
                    float a4 = 0.f;
                    #pragma unroll
                    for (int j = 0; j < 11; ++j) {
                        const int sl = (s + 1 + j) % 11;   // static per (s,j)
                        a01 = __builtin_elementwise_fma(wp[j], hist01[sl], a01);
                        a23 = __builtin_elementwise_fma(wp[j], hist23[sl], a23);
                        a4 = fmaf(wp[j][0], hist4[sl], a4);
                    }
                    float mx = a01[0], my = a01[1];
                    float mxx = mx * mx, myy = my * my, mxy = mx * my;
                    float sxx = a23[0] - mxx, syy = a23[1] - myy, sxy = a4 - mxy;
                    float num = (2.f * mxy + C1) * (2.f * sxy + C2);
                    float den = (mxx + myy + C1) * (sxx + syy + C2);
                    lsum += num * __builtin_amdgcn_rcpf(den);
                }
            }
        }

        __syncthreads();                    // everyone done reading tile
        if (c < NCHUNK - 1) { store_chunk(); __syncthreads(); }
    }

    // ---- reduction: wave shuffle -> LDS -> block partial -> fp64 atomic ----
    #pragma unroll
    for (int off = 32; off > 0; off >>= 1)
        lsum += __shfl_down(lsum, off, 64);
    if ((tid & 63) == 0) wavesum[tid >> 6] = lsum;
    __syncthreads();
    if (tid == 0) {
        float bs = wavesum[0] + wavesum[1] + wavesum[2] + wavesum[3];
        atomicAdd(acc_ws, (double)bs);
        __threadfence();
        unsigned long long old = atomicAdd(ctr, 1ull);
        if (old == (unsigned long long)(NBLOCKS - 1)) {
            __threadfence();
            double total = atomicAdd(acc_ws, 0.0);   // atomic RMW sees all prior adds
            out[0] = (float)(1.0 - total / NPIX);
        }
    }
}

extern "C" void kernel_launch(void* const* d_in, const int* in_sizes, int n_in,
                              void* d_out, int out_size, void* d_ws, size_t ws_size,
                              hipStream_t stream) {
    const float* x = (const float*)d_in[0];   // heatmap_clean
    const float* y = (const float*)d_in[1];   // heatmap_adv
    float* out = (float*)d_out;
    double* acc = (double*)d_ws;
    unsigned long long* ctr = (unsigned long long*)((char*)d_ws + 8);

    // zero the 16B of accumulator+counter state (capture-safe async memset)
    hipMemsetAsync(d_ws, 0, 16, stream);

    GaussW gw;
    double g[11], s = 0.0;
    for (int i = 0; i < 11; ++i) { double d = i - 5; g[i] = exp(-(d * d) / 4.5); s += g[i]; }
    for (int i = 0; i < 11; ++i) gw.w[i] = (float)(g[i] / s);

    dim3 grid(2, IMG / BROWS, 32);   // (2, 16, 32) = 1024 blocks
    ssim_stream_kernel<<<grid, 256, 0, stream>>>(x, y, acc, ctr, out, gw);
}